// Round 1
// baseline (677.633 us; speedup 1.0000x reference)
//
#include <hip/hip_runtime.h>

// Problem constants (from reference)
#define M_PTS   16385     // int(65536*0.25)+1
#define K_NB    16
#define CIN_C   256
#define COUT_C  512
#define LN_EPS  1e-5f

#define OUT_XYZ_ELEMS (M_PTS * 3)                     // 49155
#define OUT_FEAT_OFF  OUT_XYZ_ELEMS
#define OUT_NOFF_IDX  (OUT_XYZ_ELEMS + M_PTS * COUT_C) // 8438275

typedef __attribute__((ext_vector_type(8))) short bf16x8;   // 8 bf16 = 4 VGPRs
typedef __attribute__((ext_vector_type(4))) float f32x4;    // MFMA 16x16 accum

// LDS row stride in shorts: 256 + 8 pad -> 528 B row stride -> bank step 4
// -> a-frag ds_read_b128 across 16 rows is only 2-way bank-aliased (free, m136)
#define LDS_STRIDE 264

__device__ __forceinline__ ushort f2bf(float f) {
  unsigned u = __float_as_uint(f);
  u += 0x7FFFu + ((u >> 16) & 1u);   // round-to-nearest-even
  return (ushort)(u >> 16);
}

// Prep: lin_w f32->bf16 into ws; n_xyz gather; n_offset scalar.
__global__ void prep_kernel(const float* __restrict__ lin_w,
                            const float* __restrict__ xyz,
                            const int*   __restrict__ samp_idx,
                            const int*   __restrict__ offset,
                            ushort* __restrict__ lw_bf,
                            float*  __restrict__ out) {
  int tid = blockIdx.x * 256 + threadIdx.x;
  if (tid < COUT_C * CIN_C) lw_bf[tid] = f2bf(lin_w[tid]);
  if (tid < OUT_XYZ_ELEMS) {
    int p = tid / 3;
    int c = tid - p * 3;
    out[tid] = xyz[(size_t)samp_idx[p] * 3 + c];
  }
  if (tid == 0) out[OUT_NOFF_IDX] = (float)(offset[0] / 4 + 1);
}

// Main fused kernel: gather + LayerNorm -> LDS(bf16) -> MFMA GEMM -> maxpool.
// Block = 256 threads = 4 waves; wave w owns point p = blockIdx.x*4 + w.
// blockIdx.y selects a 128-wide COUT tile (4 tiles total).
__global__ __launch_bounds__(256, 4)
void td_main(const float*  __restrict__ feats,
             const float*  __restrict__ norm_w,
             const float*  __restrict__ norm_b,
             const ushort* __restrict__ lw_bf,
             const int*    __restrict__ knn,
             float* __restrict__ out) {
  __shared__ ushort lds[64 * LDS_STRIDE];   // 33792 B -> 4 blocks/CU

  const int lane = threadIdx.x & 63;
  const int w    = threadIdx.x >> 6;
  const int p    = blockIdx.x * 4 + w;
  if (p >= M_PTS) return;                   // no barriers in kernel: safe

  const int ybase = blockIdx.y * 128;
  const int quad  = lane >> 4;              // 0..3
  const int lcol  = lane & 15;              // 0..15

  // ---- Phase 1: gather + LayerNorm 16 neighbor rows into wave-private LDS
  const float4 nw = ((const float4*)norm_w)[lane];   // channels lane*4..+3
  const float4 nb = ((const float4*)norm_b)[lane];
  ushort* myrow0 = &lds[w * 16 * LDS_STRIDE];

  for (int r = 0; r < K_NB; ++r) {
    int nidx = knn[p * K_NB + r];                    // wave-uniform -> s_load
    float4 g = ((const float4*)(feats + (size_t)nidx * CIN_C))[lane];
    float s1 = g.x + g.y + g.z + g.w;
    float s2 = g.x * g.x + g.y * g.y + g.z * g.z + g.w * g.w;
#pragma unroll
    for (int off = 32; off; off >>= 1) {
      s1 += __shfl_xor(s1, off, 64);
      s2 += __shfl_xor(s2, off, 64);
    }
    float mu  = s1 * (1.0f / 256.0f);
    float var = fmaf(-mu, mu, s2 * (1.0f / 256.0f));
    float rs  = rsqrtf(var + LN_EPS);
    ushort4 o4;
    o4.x = f2bf(fmaf((g.x - mu) * rs, nw.x, nb.x));
    o4.y = f2bf(fmaf((g.y - mu) * rs, nw.y, nb.y));
    o4.z = f2bf(fmaf((g.z - mu) * rs, nw.z, nb.z));
    o4.w = f2bf(fmaf((g.w - mu) * rs, nw.w, nb.w));
    *(ushort4*)&myrow0[r * LDS_STRIDE + lane * 4] = o4;   // 8B ds_write
  }
  // Wave-private LDS region: same-wave write->read, compiler emits lgkmcnt.

  // ---- Phase 2: [16 x 256] @ lin_w^T[256 x 128-tile] via mfma 16x16x32
  f32x4 acc[8];
#pragma unroll
  for (int ct = 0; ct < 8; ++ct) acc[ct] = (f32x4){0.f, 0.f, 0.f, 0.f};

  const bf16x8* B8 = (const bf16x8*)lw_bf;           // [o][c/8]
  const ushort* arow = &myrow0[lcol * LDS_STRIDE];   // A row m = lane&15

#pragma unroll
  for (int kk = 0; kk < 8; ++kk) {                   // K chunks of 32
    bf16x8 af = *(const bf16x8*)&arow[kk * 32 + quad * 8];  // ds_read_b128
#pragma unroll
    for (int ct = 0; ct < 8; ++ct) {
      int o = ybase + ct * 16 + lcol;                // B col n = lane&15
      bf16x8 bf = B8[o * 32 + kk * 4 + quad];        // 16B L2-resident load
      acc[ct] = __builtin_amdgcn_mfma_f32_16x16x32_bf16(af, bf, acc[ct], 0, 0, 0);
    }
  }

  // ---- Phase 3: maxpool over the 16 D-rows (= 16 neighbors) per col
  // D layout: col = lane&15, row = quad*4 + reg  -> reduce regs then quads.
  float* outp = out + OUT_FEAT_OFF;
#pragma unroll
  for (int ct = 0; ct < 8; ++ct) {
    float v = fmaxf(fmaxf(acc[ct][0], acc[ct][1]), fmaxf(acc[ct][2], acc[ct][3]));
    v = fmaxf(v, __shfl_xor(v, 16, 64));
    v = fmaxf(v, __shfl_xor(v, 32, 64));
    if (quad == 0)
      outp[(size_t)p * COUT_C + ybase + ct * 16 + lcol] = v;
  }
}

extern "C" void kernel_launch(void* const* d_in, const int* in_sizes, int n_in,
                              void* d_out, int out_size, void* d_ws, size_t ws_size,
                              hipStream_t stream) {
  const float* xyz      = (const float*)d_in[0];
  const float* feats    = (const float*)d_in[1];
  const float* norm_w   = (const float*)d_in[2];
  const float* norm_b   = (const float*)d_in[3];
  const float* lin_w    = (const float*)d_in[4];
  const int*   samp_idx = (const int*)d_in[5];
  const int*   knn      = (const int*)d_in[6];
  const int*   offset   = (const int*)d_in[7];
  float*  out   = (float*)d_out;
  ushort* lw_bf = (ushort*)d_ws;                    // 512*256*2 = 256 KB

  prep_kernel<<<512, 256, 0, stream>>>(lin_w, xyz, samp_idx, offset, lw_bf, out);

  dim3 grid((M_PTS + 3) / 4, 4);                    // 4097 point-tiles x 4 o-tiles
  td_main<<<grid, 256, 0, stream>>>(feats, norm_w, norm_b, lw_bf, knn, out);
}

// Round 2
// 307.471 us; speedup vs baseline: 2.2039x; 2.2039x over previous
//
#include <hip/hip_runtime.h>

// Problem constants (from reference)
#define M_PTS   16385     // int(65536*0.25)+1
#define K_NB    16
#define CIN_C   256
#define COUT_C  512
#define LN_EPS  1e-5f

#define OUT_XYZ_ELEMS (M_PTS * 3)                      // 49155
#define OUT_FEAT_OFF  OUT_XYZ_ELEMS
#define OUT_NOFF_IDX  (OUT_XYZ_ELEMS + M_PTS * COUT_C) // 8438275

typedef __attribute__((ext_vector_type(8))) short bf16x8;   // 8 bf16 = 4 VGPRs
typedef __attribute__((ext_vector_type(4))) float f32x4;    // MFMA 16x16 accum

// A-tile LDS row stride in ushorts: 264 -> 528 B. Bank check for the
// A-frag ds_read_b128 (addr = row*528 + kk*64 + quad*16): dword index mod 32
// = (4*(lcol+quad)+j) -> every bank hit exactly 8x -> conflict-free.
#define LDS_STRIDE 264

__device__ __forceinline__ ushort f2bf(float f) {
  unsigned u = __float_as_uint(f);
  u += 0x7FFFu + ((u >> 16) & 1u);   // round-to-nearest-even
  return (ushort)(u >> 16);
}

// async global->LDS, 16B per lane. LDS dest = wave-uniform base + lane*16.
__device__ __forceinline__ void async_copy16(const void* g, void* l) {
  __builtin_amdgcn_global_load_lds(
      (const __attribute__((address_space(1))) unsigned*)g,
      (__attribute__((address_space(3))) unsigned*)l, 16, 0, 0);
}

// Prep: lin_w f32->bf16 into ws with a [chunk][kk][o_local][c&31] tile-swizzle
// so the main kernel's B staging is a LINEAR 32KB copy (global_load_lds needs
// lane-contiguous dest) AND the B-frag ds_read_b128s are conflict-free.
// Also: n_xyz gather and n_offset scalar.
__global__ void prep_kernel(const float* __restrict__ lin_w,
                            const float* __restrict__ xyz,
                            const int*   __restrict__ samp_idx,
                            const int*   __restrict__ offset,
                            ushort* __restrict__ lw_sw,
                            float*  __restrict__ out) {
  int tid = blockIdx.x * 256 + threadIdx.x;
  if (tid < COUT_C * CIN_C) {
    int o = tid >> 8;          // 0..511
    int c = tid & 255;         // 0..255
    // pos = [o>>6][c>>5][o&63][c&31]
    int pos = ((o >> 6) << 14) + ((c >> 5) << 11) + ((o & 63) << 5) + (c & 31);
    lw_sw[pos] = f2bf(lin_w[tid]);
  }
  if (tid < OUT_XYZ_ELEMS) {
    int p = tid / 3;
    int c = tid - p * 3;
    out[tid] = xyz[(size_t)samp_idx[p] * 3 + c];
  }
  if (tid == 0) out[OUT_NOFF_IDX] = (float)(offset[0] / 4 + 1);
}

// Fused: gather + LayerNorm -> LDS A (bf16) -> MFMA GEMM (B chunk-staged in
// LDS, shared by the block's 4 waves) -> maxpool-16 -> store.
// Block = 4 waves = 4 points; each wave computes ALL 512 output cols.
__global__ __launch_bounds__(256, 2)
void td_main(const float*  __restrict__ feats,
             const float*  __restrict__ norm_w,
             const float*  __restrict__ norm_b,
             const ushort* __restrict__ lw_sw,
             const int*    __restrict__ knn,
             float* __restrict__ out) {
  __shared__ ushort Alds[64 * LDS_STRIDE];   // 33792 B
  __shared__ ushort Blds[16384];             // 32768 B  -> total 66560, 2 blk/CU

  const int tid  = threadIdx.x;
  const int lane = tid & 63;
  const int w    = tid >> 6;
  int p = blockIdx.x * 4 + w;
  if (p >= M_PTS) p = M_PTS - 1;   // tail: duplicate work, keeps barriers legal

  // ---- Phase 1: gather + LayerNorm, lane = (row r, quarter q of channels)
  const int r = lane >> 2;         // neighbor row 0..15
  const int q = lane & 3;          // channel quarter (64 ch each)

  const int nidx = knn[p * K_NB + r];
  const float4* src = (const float4*)(feats + (size_t)nidx * CIN_C + q * 64);
  float4 g[16];
#pragma unroll
  for (int i = 0; i < 16; ++i) g[i] = src[i];      // all 16KB/wave in flight

  float s1 = 0.f, s2 = 0.f;
#pragma unroll
  for (int i = 0; i < 16; ++i) {
    s1 += (g[i].x + g[i].y) + (g[i].z + g[i].w);
    s2 += g[i].x * g[i].x + g[i].y * g[i].y + g[i].z * g[i].z + g[i].w * g[i].w;
  }
  s1 += __shfl_xor(s1, 1, 64);  s2 += __shfl_xor(s2, 1, 64);
  s1 += __shfl_xor(s1, 2, 64);  s2 += __shfl_xor(s2, 2, 64);
  const float mu  = s1 * (1.0f / 256.0f);
  const float var = fmaf(-mu, mu, s2 * (1.0f / 256.0f));
  const float rs  = rsqrtf(var + LN_EPS);

  ushort* dst = &Alds[(w * 16 + r) * LDS_STRIDE + q * 64];
  const float4* nw4 = (const float4*)norm_w;
  const float4* nb4 = (const float4*)norm_b;
#pragma unroll
  for (int j = 0; j < 8; ++j) {
    float4 a = g[2 * j], b = g[2 * j + 1];
    float4 wa = nw4[q * 16 + 2 * j], wb = nw4[q * 16 + 2 * j + 1];
    float4 ba = nb4[q * 16 + 2 * j], bb = nb4[q * 16 + 2 * j + 1];
    bf16x8 o;
    o[0] = (short)f2bf(fmaf((a.x - mu) * rs, wa.x, ba.x));
    o[1] = (short)f2bf(fmaf((a.y - mu) * rs, wa.y, ba.y));
    o[2] = (short)f2bf(fmaf((a.z - mu) * rs, wa.z, ba.z));
    o[3] = (short)f2bf(fmaf((a.w - mu) * rs, wa.w, ba.w));
    o[4] = (short)f2bf(fmaf((b.x - mu) * rs, wb.x, bb.x));
    o[5] = (short)f2bf(fmaf((b.y - mu) * rs, wb.y, bb.y));
    o[6] = (short)f2bf(fmaf((b.z - mu) * rs, wb.z, bb.z));
    o[7] = (short)f2bf(fmaf((b.w - mu) * rs, wb.w, bb.w));
    *(bf16x8*)(dst + j * 8) = o;    // ds_write_b128, conflict-free
  }

  // ---- Phase 2: [16 x 256] @ B^T chunks of 64 cols, B staged in LDS
  const int quad = lane >> 4;      // 0..3
  const int lcol = lane & 15;      // 0..15

  f32x4 acc[32];
#pragma unroll
  for (int t = 0; t < 32; ++t) acc[t] = (f32x4){0.f, 0.f, 0.f, 0.f};

  const ushort* arow = &Alds[(w * 16 + lcol) * LDS_STRIDE];

#pragma unroll
  for (int chunk = 0; chunk < 8; ++chunk) {
    __syncthreads();               // prev chunk's B reads done before overwrite
    const ushort* gsrc = lw_sw + chunk * 16384 + tid * 8;
#pragma unroll
    for (int i = 0; i < 8; ++i)    // 32KB linear: 8 x (256 thr x 16B)
      async_copy16(gsrc + i * 2048, &Blds[i * 2048 + w * 512]);
    __syncthreads();               // drains vmcnt -> B visible to all waves

#pragma unroll
    for (int kk = 0; kk < 8; ++kk) {
      bf16x8 af = *(const bf16x8*)&arow[kk * 32 + quad * 8];
#pragma unroll
      for (int ct = 0; ct < 4; ++ct) {
        // Blds[kk][o_local = ct*16+lcol][quad*8..]: lane-contiguous -> no conflicts
        bf16x8 bf = *(const bf16x8*)&Blds[kk * 2048 + (ct * 16 + lcol) * 32 + quad * 8];
        acc[chunk * 4 + ct] =
            __builtin_amdgcn_mfma_f32_16x16x32_bf16(af, bf, acc[chunk * 4 + ct], 0, 0, 0);
      }
    }
  }

  // ---- Phase 3: maxpool over 16 D-rows (neighbors), store 512 cols
  // D layout: col = lane&15, row = quad*4 + reg
  float* outp = out + OUT_FEAT_OFF + (size_t)p * COUT_C;
#pragma unroll
  for (int chunk = 0; chunk < 8; ++chunk) {
#pragma unroll
    for (int ct = 0; ct < 4; ++ct) {
      f32x4 a = acc[chunk * 4 + ct];
      float v = fmaxf(fmaxf(a[0], a[1]), fmaxf(a[2], a[3]));
      v = fmaxf(v, __shfl_xor(v, 16, 64));
      v = fmaxf(v, __shfl_xor(v, 32, 64));
      if (quad == 0) outp[chunk * 64 + ct * 16 + lcol] = v;
    }
  }
}

extern "C" void kernel_launch(void* const* d_in, const int* in_sizes, int n_in,
                              void* d_out, int out_size, void* d_ws, size_t ws_size,
                              hipStream_t stream) {
  const float* xyz      = (const float*)d_in[0];
  const float* feats    = (const float*)d_in[1];
  const float* norm_w   = (const float*)d_in[2];
  const float* norm_b   = (const float*)d_in[3];
  const float* lin_w    = (const float*)d_in[4];
  const int*   samp_idx = (const int*)d_in[5];
  const int*   knn      = (const int*)d_in[6];
  const int*   offset   = (const int*)d_in[7];
  float*  out   = (float*)d_out;
  ushort* lw_sw = (ushort*)d_ws;                    // 512*256*2 = 256 KB

  prep_kernel<<<512, 256, 0, stream>>>(lin_w, xyz, samp_idx, offset, lw_sw, out);

  dim3 grid((M_PTS + 3) / 4);                       // 4097 blocks x 4 points
  td_main<<<grid, 256, 0, stream>>>(feats, norm_w, norm_b, lw_sw, knn, out);
}

// Round 3
// 218.415 us; speedup vs baseline: 3.1025x; 1.4077x over previous
//
#include <hip/hip_runtime.h>

// Problem constants (from reference)
#define M_PTS   16385     // int(65536*0.25)+1
#define K_NB    16
#define CIN_C   256
#define COUT_C  512
#define LN_EPS  1e-5f

#define OUT_XYZ_ELEMS (M_PTS * 3)                      // 49155
#define OUT_FEAT_OFF  OUT_XYZ_ELEMS
#define OUT_NOFF_IDX  (OUT_XYZ_ELEMS + M_PTS * COUT_C) // 8438275

#define NBLK 256          // persistent-ish: 1 block per CU
#define PPB  65           // ceil(16385/256) points per block

typedef __attribute__((ext_vector_type(8))) short bf16x8;   // 8 bf16 = 4 VGPRs
typedef __attribute__((ext_vector_type(4))) float f32x4;    // MFMA 16x16 accum

// A-tile row stride (ushorts): 264 -> 528 B; near-minimal banking for both
// the ds_write_b128 (phase 1) and the A-frag ds_read_b128 (phase 2).
#define LDS_STRIDE 264

__device__ __forceinline__ ushort f2bf(float f) {
  unsigned u = __float_as_uint(f);
  u += 0x7FFFu + ((u >> 16) & 1u);   // round-to-nearest-even
  return (ushort)(u >> 16);
}

// Barrier WITHOUT the compiler's vmcnt(0) drain: LDS writes must be visible
// (lgkmcnt(0)), but in-flight global prefetch loads may cross the barrier.
__device__ __forceinline__ void block_sync_lds() {
  asm volatile("s_waitcnt lgkmcnt(0)" ::: "memory");
  __builtin_amdgcn_s_barrier();
}

// Prep: lin_w f32->bf16 into ws, swizzled so each wave's persistent B-register
// load is perfectly coalesced (1KB per instruction):
//   pos = [chunk=o>>6][ct=(o>>4)&3][kk=c>>5][quad=(c>>3)&3][lcol=o&15][e=c&7]
// Element at (lane=quad*16+lcol, reg e) of Breg[kk][ct] for wave chunk
// = lin_w[o = chunk*64+ct*16+lcol][c = kk*32+quad*8+e]  (same fragment
// semantics as R2, which validated).
// Also: n_xyz gather and n_offset scalar.
__global__ void prep_kernel(const float* __restrict__ lin_w,
                            const float* __restrict__ xyz,
                            const int*   __restrict__ samp_idx,
                            const int*   __restrict__ offset,
                            ushort* __restrict__ lw_sw,
                            float*  __restrict__ out) {
  int tid = blockIdx.x * 256 + threadIdx.x;
  if (tid < COUT_C * CIN_C) {
    int o = tid >> 8;          // 0..511
    int c = tid & 255;         // 0..255
    int pos = ((o >> 6) << 14) | (((o >> 4) & 3) << 12) | ((c >> 5) << 9)
            | (((c >> 3) & 3) << 7) | ((o & 15) << 3) | (c & 7);
    lw_sw[pos] = f2bf(lin_w[tid]);
  }
  if (tid < OUT_XYZ_ELEMS) {
    int p = tid / 3;
    int c = tid - p * 3;
    out[tid] = xyz[(size_t)samp_idx[p] * 3 + c];
  }
  if (tid == 0) out[OUT_NOFF_IDX] = (float)(offset[0] / 4 + 1);
}

// Fused main: block = 512 threads = 8 waves. Wave w owns output cols
// [w*64, w*64+64) with its B-chunk resident in 128 VGPRs. Block processes
// points [blk*PPB, ...): per point, all 512 threads gather+LayerNorm the
// 16x256 A-tile into double-buffered LDS; each wave then runs
// 8 ds_read_b128 + 32 MFMA from registers, maxpools 16 rows, stores.
__global__ __launch_bounds__(512, 2)
void td_main(const float*  __restrict__ feats,
             const float*  __restrict__ norm_w,
             const float*  __restrict__ norm_b,
             const ushort* __restrict__ lw_sw,
             const int*    __restrict__ knn,
             float* __restrict__ out) {
  __shared__ ushort A[2][16 * LDS_STRIDE];   // 2 x 8448 B
  __shared__ int Kidx[PPB * K_NB];           // 4160 B

  const int tid  = threadIdx.x;
  const int lane = tid & 63;
  const int w    = tid >> 6;        // wave = 64-col chunk
  const int quad = lane >> 4;
  const int lcol = lane & 15;

  const int pstart = blockIdx.x * PPB;
  const int pend   = min(pstart + PPB, M_PTS);
  const int npts   = pend - pstart;
  if (npts <= 0) return;            // whole block exits together (253..255)

  // Stage this block's knn indices (removes dependent idx->feats chains)
  for (int i = tid; i < npts * K_NB; i += 512)
    Kidx[i] = knn[pstart * K_NB + i];

  // Persistent B chunk: Breg[kk][ct], 128 VGPRs, coalesced 1KB loads
  bf16x8 Breg[8][4];
  {
    const ushort* base = lw_sw + (w << 14) + lane * 8;
#pragma unroll
    for (int ct = 0; ct < 4; ++ct)
#pragma unroll
      for (int kk = 0; kk < 8; ++kk)
        Breg[kk][ct] = *(const bf16x8*)(base + (ct << 12) + (kk << 9));
  }

  // Phase-1 mapping: row r = tid>>5 (16 rows), 32 threads/row, 8 ch each
  const int r  = tid >> 5;
  const int cq = tid & 31;
  const float4 nw0 = ((const float4*)norm_w)[cq * 2];
  const float4 nw1 = ((const float4*)norm_w)[cq * 2 + 1];
  const float4 nb0 = ((const float4*)norm_b)[cq * 2];
  const float4 nb1 = ((const float4*)norm_b)[cq * 2 + 1];

  __syncthreads();                  // Kidx visible

  // Prefetch point 0's feats (32B/thread)
  float4 c0, c1;
  {
    const float4* s = (const float4*)(feats + (size_t)Kidx[r] * CIN_C) + cq * 2;
    c0 = s[0]; c1 = s[1];
  }

  for (int lp = 0; lp < npts; ++lp) {
    // Prefetch next point (in flight across the barrier: block_sync_lds
    // does NOT drain vmcnt)
    float4 n0 = {0,0,0,0}, n1 = {0,0,0,0};
    if (lp + 1 < npts) {
      const float4* s =
          (const float4*)(feats + (size_t)Kidx[(lp + 1) * K_NB + r] * CIN_C) + cq * 2;
      n0 = s[0]; n1 = s[1];
    }

    // LayerNorm current point's row r (stats across 32 threads of the row)
    float s1 = (c0.x + c0.y + c0.z + c0.w) + (c1.x + c1.y + c1.z + c1.w);
    float s2 = c0.x*c0.x + c0.y*c0.y + c0.z*c0.z + c0.w*c0.w
             + c1.x*c1.x + c1.y*c1.y + c1.z*c1.z + c1.w*c1.w;
    s1 += __shfl_xor(s1, 1, 64);  s2 += __shfl_xor(s2, 1, 64);
    s1 += __shfl_xor(s1, 2, 64);  s2 += __shfl_xor(s2, 2, 64);
    s1 += __shfl_xor(s1, 4, 64);  s2 += __shfl_xor(s2, 4, 64);
    s1 += __shfl_xor(s1, 8, 64);  s2 += __shfl_xor(s2, 8, 64);
    s1 += __shfl_xor(s1, 16, 64); s2 += __shfl_xor(s2, 16, 64);
    const float mu  = s1 * (1.0f / 256.0f);
    const float var = fmaf(-mu, mu, s2 * (1.0f / 256.0f));
    const float rs  = rsqrtf(var + LN_EPS);

    bf16x8 o;
    o[0] = (short)f2bf(fmaf((c0.x - mu) * rs, nw0.x, nb0.x));
    o[1] = (short)f2bf(fmaf((c0.y - mu) * rs, nw0.y, nb0.y));
    o[2] = (short)f2bf(fmaf((c0.z - mu) * rs, nw0.z, nb0.z));
    o[3] = (short)f2bf(fmaf((c0.w - mu) * rs, nw0.w, nb0.w));
    o[4] = (short)f2bf(fmaf((c1.x - mu) * rs, nw1.x, nb1.x));
    o[5] = (short)f2bf(fmaf((c1.y - mu) * rs, nw1.y, nb1.y));
    o[6] = (short)f2bf(fmaf((c1.z - mu) * rs, nw1.z, nb1.z));
    o[7] = (short)f2bf(fmaf((c1.w - mu) * rs, nw1.w, nb1.w));
    *(bf16x8*)&A[lp & 1][r * LDS_STRIDE + cq * 8] = o;   // ds_write_b128

    block_sync_lds();               // A visible; prefetch stays in flight

    // GEMM: A[16 rows][256] x Breg -> 64 cols; D row = quad*4+reg
    f32x4 acc[4];
#pragma unroll
    for (int ct = 0; ct < 4; ++ct) acc[ct] = (f32x4){0.f, 0.f, 0.f, 0.f};
    const ushort* arow = &A[lp & 1][lcol * LDS_STRIDE];
#pragma unroll
    for (int kk = 0; kk < 8; ++kk) {
      bf16x8 af = *(const bf16x8*)&arow[kk * 32 + quad * 8];
#pragma unroll
      for (int ct = 0; ct < 4; ++ct)
        acc[ct] = __builtin_amdgcn_mfma_f32_16x16x32_bf16(af, Breg[kk][ct],
                                                          acc[ct], 0, 0, 0);
    }

    // Maxpool over 16 neighbor rows, store 64 cols
    float* outp = out + OUT_FEAT_OFF + (size_t)(pstart + lp) * COUT_C + w * 64;
#pragma unroll
    for (int ct = 0; ct < 4; ++ct) {
      float v = fmaxf(fmaxf(acc[ct][0], acc[ct][1]), fmaxf(acc[ct][2], acc[ct][3]));
      v = fmaxf(v, __shfl_xor(v, 16, 64));
      v = fmaxf(v, __shfl_xor(v, 32, 64));
      if (quad == 0) outp[ct * 16 + lcol] = v;
    }
    // No second barrier needed: next iter writes the OTHER A buffer, and its
    // own barrier orders reuse two iterations out.
    c0 = n0; c1 = n1;
  }
}

extern "C" void kernel_launch(void* const* d_in, const int* in_sizes, int n_in,
                              void* d_out, int out_size, void* d_ws, size_t ws_size,
                              hipStream_t stream) {
  const float* xyz      = (const float*)d_in[0];
  const float* feats    = (const float*)d_in[1];
  const float* norm_w   = (const float*)d_in[2];
  const float* norm_b   = (const float*)d_in[3];
  const float* lin_w    = (const float*)d_in[4];
  const int*   samp_idx = (const int*)d_in[5];
  const int*   knn      = (const int*)d_in[6];
  const int*   offset   = (const int*)d_in[7];
  float*  out   = (float*)d_out;
  ushort* lw_sw = (ushort*)d_ws;                    // 512*256*2 = 256 KB

  prep_kernel<<<512, 256, 0, stream>>>(lin_w, xyz, samp_idx, offset, lw_sw, out);

  td_main<<<NBLK, 512, 0, stream>>>(feats, norm_w, norm_b, lw_sw, knn, out);
}

// Round 4
// 207.357 us; speedup vs baseline: 3.2680x; 1.0533x over previous
//
#include <hip/hip_runtime.h>

// Problem constants (from reference)
#define M_PTS   16385     // int(65536*0.25)+1
#define K_NB    16
#define CIN_C   256
#define COUT_C  512
#define LN_EPS  1e-5f

#define OUT_XYZ_ELEMS (M_PTS * 3)                      // 49155
#define OUT_FEAT_OFF  OUT_XYZ_ELEMS
#define OUT_NOFF_IDX  (OUT_XYZ_ELEMS + M_PTS * COUT_C) // 8438275

#define NBLK 256          // 1 block per CU
#define PPB  65           // ceil(16385/256) points per block

typedef __attribute__((ext_vector_type(8))) short bf16x8;   // 8 bf16 = 4 VGPRs
typedef __attribute__((ext_vector_type(4))) float f32x4;    // MFMA 16x16 accum

// A-tile row stride (ushorts): 264 -> 528 B (same banking family as R2/R3,
// validated: ~4M conflicts total, negligible).
#define LDS_STRIDE 264

__device__ __forceinline__ ushort f2bf(float f) {
  unsigned u = __float_as_uint(f);
  u += 0x7FFFu + ((u >> 16) & 1u);   // round-to-nearest-even
  return (ushort)(u >> 16);
}

// Barrier WITHOUT the compiler's vmcnt(0) drain: LDS writes must be visible
// (lgkmcnt(0)), but in-flight global prefetch loads may cross the barrier.
__device__ __forceinline__ void block_sync_lds() {
  asm volatile("s_waitcnt lgkmcnt(0)" ::: "memory");
  __builtin_amdgcn_s_barrier();
}

// Prep: lin_w f32->bf16 into ws, swizzled so each wave's persistent 32-col
// B-chunk load is perfectly coalesced (1KB per instruction):
//   Breg[kk][ct][e] at lane (quad*16+lcol) of wave w
//     = lin_w[o = w*32 + ct*16 + lcol][c = kk*32 + quad*8 + e]
//   pos = [w:4][ct:1][kk:3][quad:2][lcol:4][e:3]
// (same fragment semantics as R2/R3, which validated numerically).
// Also: n_xyz gather and n_offset scalar.
__global__ void prep_kernel(const float* __restrict__ lin_w,
                            const float* __restrict__ xyz,
                            const int*   __restrict__ samp_idx,
                            const int*   __restrict__ offset,
                            ushort* __restrict__ lw_sw,
                            float*  __restrict__ out) {
  int tid = blockIdx.x * 256 + threadIdx.x;
  if (tid < COUT_C * CIN_C) {
    int o = tid >> 8;          // 0..511
    int c = tid & 255;         // 0..255
    int pos = ((o >> 5) << 13) | (((o >> 4) & 1) << 12) | ((c >> 5) << 9)
            | (((c >> 3) & 3) << 7) | ((o & 15) << 3) | (c & 7);
    lw_sw[pos] = f2bf(lin_w[tid]);
  }
  if (tid < OUT_XYZ_ELEMS) {
    int p = tid / 3;
    int c = tid - p * 3;
    out[tid] = xyz[(size_t)samp_idx[p] * 3 + c];
  }
  if (tid == 0) out[OUT_NOFF_IDX] = (float)(offset[0] / 4 + 1);
}

// Fused main: block = 1024 threads = 16 waves. Wave w:
//   - owns output cols [w*32, w*32+32) with B resident in 64 VGPRs
//   - gathers + LayerNorms neighbor row w (one coalesced 1KB load, 16B/lane)
// Per point: all 16 waves write the 16x256 A-tile (double-buffered LDS),
// lgkm-only barrier, then 8 ds_read_b128 + 16 MFMA from registers,
// maxpool-16, store 32 cols. Prefetch depth 2 on the gather.
__global__ __launch_bounds__(1024, 4)
void td_main(const float*  __restrict__ feats,
             const float*  __restrict__ norm_w,
             const float*  __restrict__ norm_b,
             const ushort* __restrict__ lw_sw,
             const int*    __restrict__ knn,
             float* __restrict__ out) {
  __shared__ ushort A[2][16 * LDS_STRIDE];   // 2 x 8448 B
  __shared__ int Kidx[PPB * K_NB];           // 4160 B -> total 21056 B

  const int tid  = threadIdx.x;
  const int lane = tid & 63;
  const int w    = tid >> 6;        // wave = neighbor row AND 32-col chunk
  const int quad = lane >> 4;
  const int lcol = lane & 15;

  const int pstart = blockIdx.x * PPB;
  const int npts   = min(pstart + PPB, M_PTS) - pstart;
  if (npts <= 0) return;            // blocks 253..255 exit (before any barrier)

  // Stage this block's knn indices
  for (int i = tid; i < npts * K_NB; i += 1024)
    Kidx[i] = knn[pstart * K_NB + i];

  // Persistent B chunk: Breg[kk][ct], 64 VGPRs, coalesced 1KB loads
  bf16x8 Breg[8][2];
  {
    const ushort* base = lw_sw + (w << 13) + lane * 8;
#pragma unroll
    for (int ct = 0; ct < 2; ++ct)
#pragma unroll
      for (int kk = 0; kk < 8; ++kk)
        Breg[kk][ct] = *(const bf16x8*)(base + (ct << 12) + (kk << 9));
  }

  // LayerNorm weights for this lane's 4 channels
  const float4 nw = ((const float4*)norm_w)[lane];
  const float4 nb = ((const float4*)norm_b)[lane];

  __syncthreads();                  // Kidx visible

  // Prefetch points 0 and 1 (16B/lane each, one coalesced load per wave)
  float4 f0, f1;
  f0 = ((const float4*)(feats + (size_t)Kidx[w] * CIN_C))[lane];
  f1 = (npts > 1)
     ? ((const float4*)(feats + (size_t)Kidx[K_NB + w] * CIN_C))[lane]
     : f0;

  for (int lp = 0; lp < npts; ++lp) {
    // Prefetch point lp+2 (stays in flight across the lgkm-only barriers)
    float4 ft = f1;
    if (lp + 2 < npts)
      ft = ((const float4*)(feats + (size_t)Kidx[(lp + 2) * K_NB + w] * CIN_C))[lane];

    // LayerNorm row w of point lp (stats across the full wave = 256 ch)
    float s1 = (f0.x + f0.y) + (f0.z + f0.w);
    float s2 = f0.x * f0.x + f0.y * f0.y + f0.z * f0.z + f0.w * f0.w;
    s1 += __shfl_xor(s1, 1, 64);  s2 += __shfl_xor(s2, 1, 64);
    s1 += __shfl_xor(s1, 2, 64);  s2 += __shfl_xor(s2, 2, 64);
    s1 += __shfl_xor(s1, 4, 64);  s2 += __shfl_xor(s2, 4, 64);
    s1 += __shfl_xor(s1, 8, 64);  s2 += __shfl_xor(s2, 8, 64);
    s1 += __shfl_xor(s1, 16, 64); s2 += __shfl_xor(s2, 16, 64);
    s1 += __shfl_xor(s1, 32, 64); s2 += __shfl_xor(s2, 32, 64);
    const float mu  = s1 * (1.0f / 256.0f);
    const float var = fmaf(-mu, mu, s2 * (1.0f / 256.0f));
    const float rs  = rsqrtf(var + LN_EPS);

    ushort4 o4;
    o4.x = f2bf(fmaf((f0.x - mu) * rs, nw.x, nb.x));
    o4.y = f2bf(fmaf((f0.y - mu) * rs, nw.y, nb.y));
    o4.z = f2bf(fmaf((f0.z - mu) * rs, nw.z, nb.z));
    o4.w = f2bf(fmaf((f0.w - mu) * rs, nw.w, nb.w));
    *(ushort4*)&A[lp & 1][w * LDS_STRIDE + lane * 4] = o4;   // ds_write_b64

    block_sync_lds();               // A visible; prefetch NOT drained

    // GEMM: A[16x256] x Breg -> 32 cols; D row = quad*4+reg (validated layout)
    f32x4 acc0 = {0.f, 0.f, 0.f, 0.f}, acc1 = {0.f, 0.f, 0.f, 0.f};
    const ushort* arow = &A[lp & 1][lcol * LDS_STRIDE];
#pragma unroll
    for (int kk = 0; kk < 8; ++kk) {
      bf16x8 af = *(const bf16x8*)&arow[kk * 32 + quad * 8];
      acc0 = __builtin_amdgcn_mfma_f32_16x16x32_bf16(af, Breg[kk][0], acc0, 0, 0, 0);
      acc1 = __builtin_amdgcn_mfma_f32_16x16x32_bf16(af, Breg[kk][1], acc1, 0, 0, 0);
    }

    // Maxpool over 16 neighbor rows, store 32 cols
    float* outp = out + OUT_FEAT_OFF + (size_t)(pstart + lp) * COUT_C + w * 32;
    {
      float v = fmaxf(fmaxf(acc0[0], acc0[1]), fmaxf(acc0[2], acc0[3]));
      v = fmaxf(v, __shfl_xor(v, 16, 64));
      v = fmaxf(v, __shfl_xor(v, 32, 64));
      if (quad == 0) outp[lcol] = v;
    }
    {
      float v = fmaxf(fmaxf(acc1[0], acc1[1]), fmaxf(acc1[2], acc1[3]));
      v = fmaxf(v, __shfl_xor(v, 16, 64));
      v = fmaxf(v, __shfl_xor(v, 32, 64));
      if (quad == 0) outp[16 + lcol] = v;
    }
    // A[lp&1] reuse at lp+2 is ordered by the barrier at lp+1.
    f0 = f1; f1 = ft;
  }
}

extern "C" void kernel_launch(void* const* d_in, const int* in_sizes, int n_in,
                              void* d_out, int out_size, void* d_ws, size_t ws_size,
                              hipStream_t stream) {
  const float* xyz      = (const float*)d_in[0];
  const float* feats    = (const float*)d_in[1];
  const float* norm_w   = (const float*)d_in[2];
  const float* norm_b   = (const float*)d_in[3];
  const float* lin_w    = (const float*)d_in[4];
  const int*   samp_idx = (const int*)d_in[5];
  const int*   knn      = (const int*)d_in[6];
  const int*   offset   = (const int*)d_in[7];
  float*  out   = (float*)d_out;
  ushort* lw_sw = (ushort*)d_ws;                    // 512*256*2 = 256 KB

  prep_kernel<<<512, 256, 0, stream>>>(lin_w, xyz, samp_idx, offset, lw_sw, out);

  td_main<<<NBLK, 1024, 0, stream>>>(feats, norm_w, norm_b, lw_sw, knn, out);
}